// Round 11
// baseline (283.387 us; speedup 1.0000x reference)
//
#include <hip/hip_runtime.h>
#include <cstdint>

// MultiHeadAttention with LoRA on Q/V.  B=4,S=2048,D=1024,H=16,HD=64,RANK=16,scale=2.0
// R14: recombine measured-best halves.  R13's osum-on-VALU regressed attn
// 80.6->84.4us (moved work from the slack MFMA pipe (40%) onto the bottleneck
// VALU pipe (47%) — A/B confirmed).  Reverted: osum via onef-MFMA in-loop
// (R11 form).  Kept: prepare fusion (R12, +4.5us), attn XCD swizzle (R11,
// FETCH 139->24.6MB), P-in-register pack_bf16 + permlane{32,16}_swap (R5),
// 8 waves x 32 q-rows (R6), mask bias as MFMA C-init (R6).
// GEMMs: proven R6 128x128 2-phase form, non-swizzled.

#define D_DIM 1024
#define S_DIM 2048
#define B_DIM 4
#define H_DIM 16
#define HD_DIM 64
#define M_DIM 8192
#define LOG2E 1.44269504f

typedef __bf16 bf16;
typedef unsigned int u32;
typedef __bf16 bf16x2v __attribute__((ext_vector_type(2)));
typedef __bf16 bf16x4v __attribute__((ext_vector_type(4)));
typedef __bf16 bf16x8 __attribute__((ext_vector_type(8)));
typedef float f32x4 __attribute__((ext_vector_type(4)));

typedef __attribute__((address_space(1))) void* as1p;
typedef __attribute__((address_space(3))) void* as3p;

__device__ __forceinline__ void gll16(const void* g, void* l) {
  __builtin_amdgcn_global_load_lds((as1p)(g), (as3p)(l), 16, 0, 0);
}

__device__ __forceinline__ u32 pack_bf16(float lo, float hi) {
  bf16x2v t;
  t[0] = (bf16)lo;
  t[1] = (bf16)hi;
  return __builtin_bit_cast(u32, t);
}

// T1 swizzle — attn only (KV L2-residency mechanism).
template <int TOTAL>
__device__ __forceinline__ int xcd_swz(int flat) {
  return (flat & 7) * (TOTAL >> 3) + (flat >> 3);
}

// --------------------------- fused prepare: x->bf16 + all W preps (one launch)
// blocks 0..4095: convert x (2048 elems each)
// blocks 4096..20479: W prep; sel = (blk-4096)>>12:
//   0: Wq+lora -> wqkv[0]; 1: Wk -> wqkv[1]; 2: Wv+lora -> wqkv[2]; 3: Wo -> wo
__global__ void prepare_kernel(const float* __restrict__ x, bf16* __restrict__ xb,
                               const float* __restrict__ Wq, const float* __restrict__ Aq,
                               const float* __restrict__ Bq, const float* __restrict__ Wk,
                               const float* __restrict__ Wv, const float* __restrict__ Av,
                               const float* __restrict__ Bv, const float* __restrict__ Wo,
                               bf16* __restrict__ wqkv, bf16* __restrict__ wo) {
  const int blk = blockIdx.x;
  if (blk < 4096) {
    const int i = (blk * 256 + threadIdx.x) * 8;
    const float4 a = *(const float4*)(x + i);
    const float4 b = *(const float4*)(x + i + 4);
    bf16x8 o;
    o[0] = (bf16)a.x; o[1] = (bf16)a.y; o[2] = (bf16)a.z; o[3] = (bf16)a.w;
    o[4] = (bf16)b.x; o[5] = (bf16)b.y; o[6] = (bf16)b.z; o[7] = (bf16)b.w;
    *(bf16x8*)(xb + i) = o;
  } else {
    const int bb = blk - 4096;
    const int sel = bb >> 12;  // uniform per block
    const int i = (bb & 4095) * 256 + threadIdx.x;
    const int n = i >> 10, k = i & (D_DIM - 1);
    const float* W = (sel == 0) ? Wq : (sel == 1) ? Wk : (sel == 2) ? Wv : Wo;
    float w = W[i];
    if (sel == 0 || sel == 2) {
      const float* A = (sel == 0) ? Aq : Av;
      const float* Bm = (sel == 0) ? Bq : Bv;
      float acc = 0.f;
#pragma unroll
      for (int r = 0; r < 16; ++r) acc = fmaf(Bm[n * 16 + r], A[r * D_DIM + k], acc);
      w += 2.0f * acc;  // SCALING = 32/16
    }
    bf16* out = (sel == 3) ? wo : wqkv + (size_t)sel * D_DIM * D_DIM;
    out[i] = (bf16)w;
  }
}

// ----------------------------------------------- fused QKV GEMM (N=3072), dbuf
// Wqkv = [wq;wk;wv] rows.  Q gets *0.125*log2e and [B,H,S,64] layout; K same
// layout unscaled; V -> [B,H,64,S] transposed (b64-packed stores).
__global__ __launch_bounds__(256) void gemm_qkv_kernel(
    const bf16* __restrict__ X, const bf16* __restrict__ Wqkv,
    const float* __restrict__ bq, const float* __restrict__ bk,
    const float* __restrict__ bv, bf16* __restrict__ Qo, bf16* __restrict__ Ko,
    bf16* __restrict__ Vo) {
  __shared__ __attribute__((aligned(16))) bf16 As[2][128 * 64];
  __shared__ __attribute__((aligned(16))) bf16 Bs[2][128 * 64];
  const int tid = threadIdx.x;
  const int wave = tid >> 6, lane = tid & 63;
  const int quad = lane >> 4, l16 = lane & 15;
  const int m0 = blockIdx.x * 128, n0 = blockIdx.y * 128;
  const int wm = (wave >> 1) * 64, wn = (wave & 1) * 64;
  const int srow = lane >> 3, sblk = lane & 7;

  const f32x4 zero = {0.f, 0.f, 0.f, 0.f};
  f32x4 acc[4][4];
#pragma unroll
  for (int mi = 0; mi < 4; ++mi)
#pragma unroll
    for (int ni = 0; ni < 4; ++ni) acc[mi][ni] = zero;

  auto stage = [&](int kt) {
    const int buf = kt & 1, kb = kt * 64;
#pragma unroll
    for (int it = 0; it < 4; ++it) {
      const int c = it * 4 + wave;
      const int row = c * 8 + srow;
      const int b = sblk ^ (row & 7);
      gll16(X + (size_t)(m0 + row) * D_DIM + kb + b * 8, &As[buf][c * 512 + lane * 8]);
      gll16(Wqkv + (size_t)(n0 + row) * D_DIM + kb + b * 8, &Bs[buf][c * 512 + lane * 8]);
    }
  };
  stage(0);

  for (int kt = 0; kt < D_DIM / 64; ++kt) {
    __syncthreads();  // vmcnt drain: tile kt landed (all waves)
    if (kt + 1 < D_DIM / 64) stage(kt + 1);
    const bf16* as_ = &As[kt & 1][0];
    const bf16* bs_ = &Bs[kt & 1][0];
#pragma unroll
    for (int ks = 0; ks < 2; ++ks) {
      bf16x8 af[4], bfr[4];
#pragma unroll
      for (int mi = 0; mi < 4; ++mi) {
        const int row = wm + mi * 16 + l16;
        af[mi] = *(const bf16x8*)(as_ + row * 64 + (((ks * 4 + quad) ^ (row & 7)) * 8));
      }
#pragma unroll
      for (int ni = 0; ni < 4; ++ni) {
        const int row = wn + ni * 16 + l16;
        bfr[ni] = *(const bf16x8*)(bs_ + row * 64 + (((ks * 4 + quad) ^ (row & 7)) * 8));
      }
#pragma unroll
      for (int mi = 0; mi < 4; ++mi)
#pragma unroll
        for (int ni = 0; ni < 4; ++ni)
          acc[mi][ni] =
              __builtin_amdgcn_mfma_f32_16x16x32_bf16(af[mi], bfr[ni], acc[mi][ni], 0, 0, 0);
    }
  }

  const int sel = n0 >> 10;  // uniform per block: 0=Q 1=K 2=V
  const float* bp = (sel == 0) ? bq : (sel == 1) ? bk : bv;
  const float qs = 0.125f * LOG2E;

  if (sel == 2) {  // V^T: [B,H,64,S], s contiguous -> b64 packed stores
#pragma unroll
    for (int ni = 0; ni < 4; ++ni) {
      const int c = (n0 + wn + ni * 16 + l16) & 1023;
      const int h = c >> 6, hd = c & 63;
      const float bvv = bp[c];
#pragma unroll
      for (int mi = 0; mi < 4; ++mi) {
        const int row0 = m0 + wm + mi * 16 + quad * 4;
        const int b = row0 >> 11, s0 = row0 & (S_DIM - 1);
        bf16x4v pk;
#pragma unroll
        for (int r = 0; r < 4; ++r) pk[r] = (bf16)(acc[mi][ni][r] + bvv);
        *(bf16x4v*)(Vo + ((size_t)(b * H_DIM + h) * HD_DIM + hd) * S_DIM + s0) = pk;
      }
    }
  } else {
    bf16* O = (sel == 0) ? Qo : Ko;
#pragma unroll
    for (int ni = 0; ni < 4; ++ni) {
      const int c = (n0 + wn + ni * 16 + l16) & 1023;
      const int h = c >> 6, hd = c & 63;
      const float bvv = bp[c];
#pragma unroll
      for (int mi = 0; mi < 4; ++mi) {
#pragma unroll
        for (int r = 0; r < 4; ++r) {
          const int row = m0 + wm + mi * 16 + quad * 4 + r;
          const int b = row >> 11, s = row & (S_DIM - 1);
          float v = acc[mi][ni][r] + bvv;
          if (sel == 0) v *= qs;  // fold 1/sqrt(HD)*log2e into Q
          O[((size_t)(b * H_DIM + h) * S_DIM + s) * HD_DIM + hd] = (bf16)v;
        }
      }
    }
  }
}

// ------------------------------------------------ O-projection GEMM (fp32 out)
__global__ __launch_bounds__(256) void gemm_o_kernel(const bf16* __restrict__ X,
                                                     const bf16* __restrict__ W,
                                                     const float* __restrict__ bias,
                                                     float* __restrict__ out) {
  __shared__ __attribute__((aligned(16))) bf16 As[2][128 * 64];
  __shared__ __attribute__((aligned(16))) bf16 Bs[2][128 * 64];
  const int tid = threadIdx.x;
  const int wave = tid >> 6, lane = tid & 63;
  const int quad = lane >> 4, l16 = lane & 15;
  const int m0 = blockIdx.x * 128, n0 = blockIdx.y * 128;
  const int wm = (wave >> 1) * 64, wn = (wave & 1) * 64;
  const int srow = lane >> 3, sblk = lane & 7;

  const f32x4 zero = {0.f, 0.f, 0.f, 0.f};
  f32x4 acc[4][4];
#pragma unroll
  for (int mi = 0; mi < 4; ++mi)
#pragma unroll
    for (int ni = 0; ni < 4; ++ni) acc[mi][ni] = zero;

  auto stage = [&](int kt) {
    const int buf = kt & 1, kb = kt * 64;
#pragma unroll
    for (int it = 0; it < 4; ++it) {
      const int c = it * 4 + wave;
      const int row = c * 8 + srow;
      const int b = sblk ^ (row & 7);
      gll16(X + (size_t)(m0 + row) * D_DIM + kb + b * 8, &As[buf][c * 512 + lane * 8]);
      gll16(W + (size_t)(n0 + row) * D_DIM + kb + b * 8, &Bs[buf][c * 512 + lane * 8]);
    }
  };
  stage(0);

  for (int kt = 0; kt < D_DIM / 64; ++kt) {
    __syncthreads();
    if (kt + 1 < D_DIM / 64) stage(kt + 1);
    const bf16* as_ = &As[kt & 1][0];
    const bf16* bs_ = &Bs[kt & 1][0];
#pragma unroll
    for (int ks = 0; ks < 2; ++ks) {
      bf16x8 af[4], bfr[4];
#pragma unroll
      for (int mi = 0; mi < 4; ++mi) {
        const int row = wm + mi * 16 + l16;
        af[mi] = *(const bf16x8*)(as_ + row * 64 + (((ks * 4 + quad) ^ (row & 7)) * 8));
      }
#pragma unroll
      for (int ni = 0; ni < 4; ++ni) {
        const int row = wn + ni * 16 + l16;
        bfr[ni] = *(const bf16x8*)(bs_ + row * 64 + (((ks * 4 + quad) ^ (row & 7)) * 8));
      }
#pragma unroll
      for (int mi = 0; mi < 4; ++mi)
#pragma unroll
        for (int ni = 0; ni < 4; ++ni)
          acc[mi][ni] =
              __builtin_amdgcn_mfma_f32_16x16x32_bf16(af[mi], bfr[ni], acc[mi][ni], 0, 0, 0);
    }
  }
#pragma unroll
  for (int ni = 0; ni < 4; ++ni) {
    const int col = n0 + wn + ni * 16 + l16;
    const float bv = bias[col];
#pragma unroll
    for (int mi = 0; mi < 4; ++mi)
#pragma unroll
      for (int r = 0; r < 4; ++r) {
        const int row = m0 + wm + mi * 16 + quad * 4 + r;
        out[(size_t)row * D_DIM + col] = acc[mi][ni][r] + bv;
      }
  }
}

// ------------------------------------------------------------------ attention
// Q,K [B,H,S,64] (Q pre-scaled by 0.125*log2e); Vt [B,H,64,S]; mask [B,S];
// ctx [B,S,D] bf16.  256 q/block as 8 waves x 32 q-rows (512 threads), KV tile
// 64, double-buffered.  Grid 512 blocks, XCD-swizzled (8 heads/XCD = 4MB KV,
// L2-resident).  S^T = mfma(kf, qf); mask bias is the MFMA C-init.  P -> PV
// A-frag in registers via pack_bf16 + permlane{32,16}_swap (distinct operands).
// osum via onef-MFMA (matrix pipe has slack; VALU is the bottleneck — R13 A/B).
// Softmax: p = exp2(s + mask*log2e - 16); out = (P V)/(P 1) — shift cancels.
__global__ __launch_bounds__(512, 4) void attn_kernel(const bf16* __restrict__ Q,
                                                      const bf16* __restrict__ K,
                                                      const bf16* __restrict__ Vt,
                                                      const float* __restrict__ mask,
                                                      bf16* __restrict__ ctx) {
  __shared__ __attribute__((aligned(16))) bf16 Ks[2][64 * 64];
  __shared__ __attribute__((aligned(16))) bf16 Vs[2][64 * 64];
  __shared__ __attribute__((aligned(16))) float cms[S_DIM];

  const int tid = threadIdx.x;
  const int wave = tid >> 6, lane = tid & 63;
  const int quad = lane >> 4, l16 = lane & 15;
  const int swz = xcd_swz<512>(blockIdx.y * 8 + blockIdx.x);
  const int bh = swz >> 3, b = bh >> 4, h = bh & 15;
  const int qt = swz & 7;  // 256 q-rows per block; 32 per wave

  // Q fragments in registers: 32 rows per wave
  const bf16* Qg = Q + ((size_t)bh * S_DIM + qt * 256 + wave * 32) * HD_DIM;
  bf16x8 qf[2][2];
#pragma unroll
  for (int nq = 0; nq < 2; ++nq)
#pragma unroll
    for (int ks = 0; ks < 2; ++ks)
      qf[nq][ks] = *(const bf16x8*)(Qg + (nq * 16 + l16) * HD_DIM + ks * 32 + quad * 8);

  // stage mask -> cms = mask*log2e - 16  (once; 512 threads x 4 floats)
  {
    const float* mp = mask + b * S_DIM + tid * 4;
    const float4 a = *(const float4*)(mp);
    f32x4 r0 = {fmaf(a.x, LOG2E, -16.f), fmaf(a.y, LOG2E, -16.f),
                fmaf(a.z, LOG2E, -16.f), fmaf(a.w, LOG2E, -16.f)};
    *(f32x4*)(cms + tid * 4) = r0;
  }

  bf16x8 onef;
#pragma unroll
  for (int j = 0; j < 8; ++j) onef[j] = (bf16)1.0f;

  const f32x4 zero = {0.f, 0.f, 0.f, 0.f};
  f32x4 o[2][4], osum[2];
#pragma unroll
  for (int nq = 0; nq < 2; ++nq) {
    osum[nq] = zero;
#pragma unroll
    for (int nh = 0; nh < 4; ++nh) o[nq][nh] = zero;
  }

  const bf16* Kg0 = K + (size_t)bh * S_DIM * HD_DIM;
  const bf16* Vg0 = Vt + (size_t)bh * HD_DIM * S_DIM;

  auto stage = [&](int t) {
    const int buf = t & 1;
    const bf16* Kg = Kg0 + (size_t)t * 64 * HD_DIM;
    const bf16* Vg = Vg0 + t * 64;
    const int c = wave;  // 8 chunks of 1024B, one per wave
    const int row = c * 8 + (lane >> 3);
    const int blk = (lane & 7) ^ (row & 7);
    gll16(Kg + (size_t)row * HD_DIM + blk * 8, &Ks[buf][c * 512 + lane * 8]);
    gll16(Vg + (size_t)row * S_DIM + blk * 8, &Vs[buf][c * 512 + lane * 8]);
  };
  stage(0);

  for (int t = 0; t < S_DIM / 64; ++t) {
    __syncthreads();  // per-wave vmcnt drain at barrier: tile t + cms ready
    if (t + 1 < S_DIM / 64) stage(t + 1);
    const bf16* ks_ = &Ks[t & 1][0];
    const bf16* vs_ = &Vs[t & 1][0];

#pragma unroll
    for (int half = 0; half < 2; ++half) {  // half == ks of PV; mt in {2h,2h+1}
      u32 pk[2][2][2];  // [nq][mtl][i]: packed bf16 pair, word = kv32/2
#pragma unroll
      for (int mtl = 0; mtl < 2; ++mtl) {
        const int mt = half * 2 + mtl;
        // mask bias as MFMA C-init: sc = cm (broadcast over l16)
        const f32x4 cm = *(const f32x4*)(cms + t * 64 + mt * 16 + quad * 4);
        f32x4 sc[2];
        sc[0] = cm;
        sc[1] = cm;
#pragma unroll
        for (int ks = 0; ks < 2; ++ks) {
          const int row = mt * 16 + l16;  // kv
          const bf16x8 kf =
              *(const bf16x8*)(ks_ + row * 64 + (((ks * 4 + quad) ^ (row & 7)) * 8));
#pragma unroll
          for (int nq = 0; nq < 2; ++nq)
            sc[nq] = __builtin_amdgcn_mfma_f32_16x16x32_bf16(kf, qf[nq][ks], sc[nq], 0, 0, 0);
        }
#pragma unroll
        for (int nq = 0; nq < 2; ++nq) {
          const float e0 = __builtin_amdgcn_exp2f(sc[nq][0]);
          const float e1 = __builtin_amdgcn_exp2f(sc[nq][1]);
          const float e2 = __builtin_amdgcn_exp2f(sc[nq][2]);
          const float e3 = __builtin_amdgcn_exp2f(sc[nq][3]);
          pk[nq][mtl][0] = pack_bf16(e0, e1);
          pk[nq][mtl][1] = pack_bf16(e2, e3);
        }
      }

      // V fragments for this ks-half
      bf16x8 vf[4];
#pragma unroll
      for (int nh = 0; nh < 4; ++nh) {
        const int vrow = nh * 16 + l16;
        vf[nh] = *(const bf16x8*)(vs_ + vrow * 64 + (((half * 4 + quad) ^ (vrow & 7)) * 8));
      }

      // redistribute P to A-frag layout + PV (compiler-visible builtins)
#pragma unroll
      for (int nq = 0; nq < 2; ++nq) {
        auto a0 = __builtin_amdgcn_permlane32_swap(pk[nq][0][0], pk[nq][1][0], false, false);
        auto a1 = __builtin_amdgcn_permlane32_swap(pk[nq][0][1], pk[nq][1][1], false, false);
        auto b0 = __builtin_amdgcn_permlane16_swap(a0[0], a0[1], false, false);
        auto b1 = __builtin_amdgcn_permlane16_swap(a1[0], a1[1], false, false);
        union {
          u32 w[4];
          bf16x8 v;
        } pu;
        pu.w[0] = b0[0];  // jw=0: kv quad*8 + {0,1}
        pu.w[1] = b1[0];  // jw=1: kv quad*8 + {2,3}
        pu.w[2] = b0[1];  // jw=2: kv quad*8 + {4,5}
        pu.w[3] = b1[1];  // jw=3: kv quad*8 + {6,7}
        const bf16x8 pf = pu.v;
#pragma unroll
        for (int nh = 0; nh < 4; ++nh)
          o[nq][nh] = __builtin_amdgcn_mfma_f32_16x16x32_bf16(pf, vf[nh], o[nq][nh], 0, 0, 0);
        osum[nq] = __builtin_amdgcn_mfma_f32_16x16x32_bf16(pf, onef, osum[nq], 0, 0, 0);
      }
    }
  }

  // epilogue: out = o / osum (lane-local)
#pragma unroll
  for (int nq = 0; nq < 2; ++nq)
#pragma unroll
    for (int r = 0; r < 4; ++r) {
      const float inv = 1.0f / osum[nq][r];
      const int s = qt * 256 + wave * 32 + nq * 16 + quad * 4 + r;
#pragma unroll
      for (int nh = 0; nh < 4; ++nh)
        ctx[((size_t)b * S_DIM + s) * D_DIM + h * 64 + nh * 16 + l16] =
            (bf16)(o[nq][nh][r] * inv);
    }
}

// ------------------------------------------------------------------ launch
extern "C" void kernel_launch(void* const* d_in, const int* in_sizes, int n_in,
                              void* d_out, int out_size, void* d_ws, size_t ws_size,
                              hipStream_t stream) {
  const float* x    = (const float*)d_in[0];
  const float* mask = (const float*)d_in[1];
  const float* Wq   = (const float*)d_in[2];
  const float* bq   = (const float*)d_in[3];
  const float* Aq   = (const float*)d_in[4];
  const float* Bq   = (const float*)d_in[5];
  const float* Wk   = (const float*)d_in[6];
  const float* bk   = (const float*)d_in[7];
  const float* Wv   = (const float*)d_in[8];
  const float* bv   = (const float*)d_in[9];
  const float* Av   = (const float*)d_in[10];
  const float* Bv   = (const float*)d_in[11];
  const float* Wo   = (const float*)d_in[12];
  const float* bo   = (const float*)d_in[13];
  float* out = (float*)d_out;

  // workspace (xb aliased by Cw after QKV GEMM): ~75.5 MB total
  bf16* xb   = (bf16*)d_ws;                        // 16.8 MB (dead after QKV GEMM)
  bf16* wqkv = xb + (size_t)M_DIM * D_DIM;         // 6.3 MB  [wq;wk;wv]
  bf16* wo   = wqkv + (size_t)3 * D_DIM * D_DIM;   // 2.1 MB
  bf16* Qw   = wo + (size_t)D_DIM * D_DIM;         // 16.8 MB each
  bf16* Kw   = Qw + (size_t)M_DIM * D_DIM;
  bf16* Vw   = Kw + (size_t)M_DIM * D_DIM;
  bf16* Cw   = xb;                                 // alias: ctx reuses xb

  prepare_kernel<<<4096 + 4 * D_DIM * D_DIM / 256, 256, 0, stream>>>(
      x, xb, Wq, Aq, Bq, Wk, Wv, Av, Bv, Wo, wqkv, wo);

  gemm_qkv_kernel<<<dim3(M_DIM / 128, 3 * D_DIM / 128), 256, 0, stream>>>(
      xb, wqkv, bq, bk, bv, Qw, Kw, Vw);

  attn_kernel<<<dim3(S_DIM / 256, B_DIM * H_DIM), 512, 0, stream>>>(Qw, Kw, Vw, mask, Cw);

  gemm_o_kernel<<<dim3(M_DIM / 128, D_DIM / 128), 256, 0, stream>>>(Cw, wo, bo, out);
}

// Round 12
// 281.339 us; speedup vs baseline: 1.0073x; 1.0073x over previous
//
#include <hip/hip_runtime.h>
#include <cstdint>

// MultiHeadAttention with LoRA on Q/V.  B=4,S=2048,D=1024,H=16,HD=64,RANK=16,scale=2.0
// R15: GEMM occupancy 2->4 waves/SIMD (the R6 mechanism, applied to the GEMMs):
// same 128x128/BK=64 2-phase dbuf structure, re-decomposed over 8 waves
// (512 threads, wave grid 2Mx4N, per-wave acc[4][2], 4 gll16/thread staging).
// LDS stays 64KB -> 2 blocks/CU -> 16 waves/CU = 4 waves/SIMD (was 2).
// No sync-structure change.  attn unchanged from R14 (80.7us, near structural
// floor): XCD swizzle (KV L2-resident), P-in-register permlane redistribution,
// osum on the MFMA pipe (R13 A/B: VALU is attn's bottleneck pipe), 8wavesx32q,
// mask bias as MFMA C-init.  prepare fusion (R12) kept.

#define D_DIM 1024
#define S_DIM 2048
#define B_DIM 4
#define H_DIM 16
#define HD_DIM 64
#define M_DIM 8192
#define LOG2E 1.44269504f

typedef __bf16 bf16;
typedef unsigned int u32;
typedef __bf16 bf16x2v __attribute__((ext_vector_type(2)));
typedef __bf16 bf16x4v __attribute__((ext_vector_type(4)));
typedef __bf16 bf16x8 __attribute__((ext_vector_type(8)));
typedef float f32x4 __attribute__((ext_vector_type(4)));

typedef __attribute__((address_space(1))) void* as1p;
typedef __attribute__((address_space(3))) void* as3p;

__device__ __forceinline__ void gll16(const void* g, void* l) {
  __builtin_amdgcn_global_load_lds((as1p)(g), (as3p)(l), 16, 0, 0);
}

__device__ __forceinline__ u32 pack_bf16(float lo, float hi) {
  bf16x2v t;
  t[0] = (bf16)lo;
  t[1] = (bf16)hi;
  return __builtin_bit_cast(u32, t);
}

// T1 swizzle — attn only (KV L2-residency mechanism).
template <int TOTAL>
__device__ __forceinline__ int xcd_swz(int flat) {
  return (flat & 7) * (TOTAL >> 3) + (flat >> 3);
}

// --------------------------- fused prepare: x->bf16 + all W preps (one launch)
// blocks 0..4095: convert x (2048 elems each)
// blocks 4096..20479: W prep; sel = (blk-4096)>>12:
//   0: Wq+lora -> wqkv[0]; 1: Wk -> wqkv[1]; 2: Wv+lora -> wqkv[2]; 3: Wo -> wo
__global__ void prepare_kernel(const float* __restrict__ x, bf16* __restrict__ xb,
                               const float* __restrict__ Wq, const float* __restrict__ Aq,
                               const float* __restrict__ Bq, const float* __restrict__ Wk,
                               const float* __restrict__ Wv, const float* __restrict__ Av,
                               const float* __restrict__ Bv, const float* __restrict__ Wo,
                               bf16* __restrict__ wqkv, bf16* __restrict__ wo) {
  const int blk = blockIdx.x;
  if (blk < 4096) {
    const int i = (blk * 256 + threadIdx.x) * 8;
    const float4 a = *(const float4*)(x + i);
    const float4 b = *(const float4*)(x + i + 4);
    bf16x8 o;
    o[0] = (bf16)a.x; o[1] = (bf16)a.y; o[2] = (bf16)a.z; o[3] = (bf16)a.w;
    o[4] = (bf16)b.x; o[5] = (bf16)b.y; o[6] = (bf16)b.z; o[7] = (bf16)b.w;
    *(bf16x8*)(xb + i) = o;
  } else {
    const int bb = blk - 4096;
    const int sel = bb >> 12;  // uniform per block
    const int i = (bb & 4095) * 256 + threadIdx.x;
    const int n = i >> 10, k = i & (D_DIM - 1);
    const float* W = (sel == 0) ? Wq : (sel == 1) ? Wk : (sel == 2) ? Wv : Wo;
    float w = W[i];
    if (sel == 0 || sel == 2) {
      const float* A = (sel == 0) ? Aq : Av;
      const float* Bm = (sel == 0) ? Bq : Bv;
      float acc = 0.f;
#pragma unroll
      for (int r = 0; r < 16; ++r) acc = fmaf(Bm[n * 16 + r], A[r * D_DIM + k], acc);
      w += 2.0f * acc;  // SCALING = 32/16
    }
    bf16* out = (sel == 3) ? wo : wqkv + (size_t)sel * D_DIM * D_DIM;
    out[i] = (bf16)w;
  }
}

// ----------------------------------------------- fused QKV GEMM (N=3072), dbuf
// 512 threads = 8 waves (2M x 4N), per-wave 64x32 output, acc[4][2].
// Wqkv = [wq;wk;wv] rows.  Q gets *0.125*log2e and [B,H,S,64] layout; K same
// layout unscaled; V -> [B,H,64,S] transposed (b64-packed stores).
__global__ __launch_bounds__(512, 4) void gemm_qkv_kernel(
    const bf16* __restrict__ X, const bf16* __restrict__ Wqkv,
    const float* __restrict__ bq, const float* __restrict__ bk,
    const float* __restrict__ bv, bf16* __restrict__ Qo, bf16* __restrict__ Ko,
    bf16* __restrict__ Vo) {
  __shared__ __attribute__((aligned(16))) bf16 As[2][128 * 64];
  __shared__ __attribute__((aligned(16))) bf16 Bs[2][128 * 64];
  const int tid = threadIdx.x;
  const int wave = tid >> 6, lane = tid & 63;
  const int quad = lane >> 4, l16 = lane & 15;
  const int m0 = blockIdx.x * 128, n0 = blockIdx.y * 128;
  const int wm = (wave >> 2) * 64, wn = (wave & 3) * 32;  // 2M x 4N waves
  const int srow = lane >> 3, sblk = lane & 7;

  const f32x4 zero = {0.f, 0.f, 0.f, 0.f};
  f32x4 acc[4][2];
#pragma unroll
  for (int mi = 0; mi < 4; ++mi)
#pragma unroll
    for (int ni = 0; ni < 2; ++ni) acc[mi][ni] = zero;

  auto stage = [&](int kt) {
    const int buf = kt & 1, kb = kt * 64;
#pragma unroll
    for (int it = 0; it < 2; ++it) {
      const int c = wave * 2 + it;   // 16 chunks of 1024B
      const int row = c * 8 + srow;
      const int b = sblk ^ (row & 7);
      gll16(X + (size_t)(m0 + row) * D_DIM + kb + b * 8, &As[buf][c * 512 + lane * 8]);
      gll16(Wqkv + (size_t)(n0 + row) * D_DIM + kb + b * 8, &Bs[buf][c * 512 + lane * 8]);
    }
  };
  stage(0);

  for (int kt = 0; kt < D_DIM / 64; ++kt) {
    __syncthreads();  // vmcnt drain: tile kt landed (all waves)
    if (kt + 1 < D_DIM / 64) stage(kt + 1);
    const bf16* as_ = &As[kt & 1][0];
    const bf16* bs_ = &Bs[kt & 1][0];
#pragma unroll
    for (int ks = 0; ks < 2; ++ks) {
      bf16x8 af[4], bfr[2];
#pragma unroll
      for (int mi = 0; mi < 4; ++mi) {
        const int row = wm + mi * 16 + l16;
        af[mi] = *(const bf16x8*)(as_ + row * 64 + (((ks * 4 + quad) ^ (row & 7)) * 8));
      }
#pragma unroll
      for (int ni = 0; ni < 2; ++ni) {
        const int row = wn + ni * 16 + l16;
        bfr[ni] = *(const bf16x8*)(bs_ + row * 64 + (((ks * 4 + quad) ^ (row & 7)) * 8));
      }
#pragma unroll
      for (int mi = 0; mi < 4; ++mi)
#pragma unroll
        for (int ni = 0; ni < 2; ++ni)
          acc[mi][ni] =
              __builtin_amdgcn_mfma_f32_16x16x32_bf16(af[mi], bfr[ni], acc[mi][ni], 0, 0, 0);
    }
  }

  const int sel = n0 >> 10;  // uniform per block: 0=Q 1=K 2=V
  const float* bp = (sel == 0) ? bq : (sel == 1) ? bk : bv;
  const float qs = 0.125f * LOG2E;

  if (sel == 2) {  // V^T: [B,H,64,S], s contiguous -> b64 packed stores
#pragma unroll
    for (int ni = 0; ni < 2; ++ni) {
      const int c = (n0 + wn + ni * 16 + l16) & 1023;
      const int h = c >> 6, hd = c & 63;
      const float bvv = bp[c];
#pragma unroll
      for (int mi = 0; mi < 4; ++mi) {
        const int row0 = m0 + wm + mi * 16 + quad * 4;
        const int b = row0 >> 11, s0 = row0 & (S_DIM - 1);
        bf16x4v pk;
#pragma unroll
        for (int r = 0; r < 4; ++r) pk[r] = (bf16)(acc[mi][ni][r] + bvv);
        *(bf16x4v*)(Vo + ((size_t)(b * H_DIM + h) * HD_DIM + hd) * S_DIM + s0) = pk;
      }
    }
  } else {
    bf16* O = (sel == 0) ? Qo : Ko;
#pragma unroll
    for (int ni = 0; ni < 2; ++ni) {
      const int c = (n0 + wn + ni * 16 + l16) & 1023;
      const int h = c >> 6, hd = c & 63;
      const float bvv = bp[c];
#pragma unroll
      for (int mi = 0; mi < 4; ++mi) {
#pragma unroll
        for (int r = 0; r < 4; ++r) {
          const int row = m0 + wm + mi * 16 + quad * 4 + r;
          const int b = row >> 11, s = row & (S_DIM - 1);
          float v = acc[mi][ni][r] + bvv;
          if (sel == 0) v *= qs;  // fold 1/sqrt(HD)*log2e into Q
          O[((size_t)(b * H_DIM + h) * S_DIM + s) * HD_DIM + hd] = (bf16)v;
        }
      }
    }
  }
}

// ------------------------------------------------ O-projection GEMM (fp32 out)
// 512 threads = 8 waves (2M x 4N), per-wave 64x32 output, acc[4][2].
__global__ __launch_bounds__(512, 4) void gemm_o_kernel(const bf16* __restrict__ X,
                                                        const bf16* __restrict__ W,
                                                        const float* __restrict__ bias,
                                                        float* __restrict__ out) {
  __shared__ __attribute__((aligned(16))) bf16 As[2][128 * 64];
  __shared__ __attribute__((aligned(16))) bf16 Bs[2][128 * 64];
  const int tid = threadIdx.x;
  const int wave = tid >> 6, lane = tid & 63;
  const int quad = lane >> 4, l16 = lane & 15;
  const int m0 = blockIdx.x * 128, n0 = blockIdx.y * 128;
  const int wm = (wave >> 2) * 64, wn = (wave & 3) * 32;
  const int srow = lane >> 3, sblk = lane & 7;

  const f32x4 zero = {0.f, 0.f, 0.f, 0.f};
  f32x4 acc[4][2];
#pragma unroll
  for (int mi = 0; mi < 4; ++mi)
#pragma unroll
    for (int ni = 0; ni < 2; ++ni) acc[mi][ni] = zero;

  auto stage = [&](int kt) {
    const int buf = kt & 1, kb = kt * 64;
#pragma unroll
    for (int it = 0; it < 2; ++it) {
      const int c = wave * 2 + it;
      const int row = c * 8 + srow;
      const int b = sblk ^ (row & 7);
      gll16(X + (size_t)(m0 + row) * D_DIM + kb + b * 8, &As[buf][c * 512 + lane * 8]);
      gll16(W + (size_t)(n0 + row) * D_DIM + kb + b * 8, &Bs[buf][c * 512 + lane * 8]);
    }
  };
  stage(0);

  for (int kt = 0; kt < D_DIM / 64; ++kt) {
    __syncthreads();
    if (kt + 1 < D_DIM / 64) stage(kt + 1);
    const bf16* as_ = &As[kt & 1][0];
    const bf16* bs_ = &Bs[kt & 1][0];
#pragma unroll
    for (int ks = 0; ks < 2; ++ks) {
      bf16x8 af[4], bfr[2];
#pragma unroll
      for (int mi = 0; mi < 4; ++mi) {
        const int row = wm + mi * 16 + l16;
        af[mi] = *(const bf16x8*)(as_ + row * 64 + (((ks * 4 + quad) ^ (row & 7)) * 8));
      }
#pragma unroll
      for (int ni = 0; ni < 2; ++ni) {
        const int row = wn + ni * 16 + l16;
        bfr[ni] = *(const bf16x8*)(bs_ + row * 64 + (((ks * 4 + quad) ^ (row & 7)) * 8));
      }
#pragma unroll
      for (int mi = 0; mi < 4; ++mi)
#pragma unroll
        for (int ni = 0; ni < 2; ++ni)
          acc[mi][ni] =
              __builtin_amdgcn_mfma_f32_16x16x32_bf16(af[mi], bfr[ni], acc[mi][ni], 0, 0, 0);
    }
  }
#pragma unroll
  for (int ni = 0; ni < 2; ++ni) {
    const int col = n0 + wn + ni * 16 + l16;
    const float bv = bias[col];
#pragma unroll
    for (int mi = 0; mi < 4; ++mi)
#pragma unroll
      for (int r = 0; r < 4; ++r) {
        const int row = m0 + wm + mi * 16 + quad * 4 + r;
        out[(size_t)row * D_DIM + col] = acc[mi][ni][r] + bv;
      }
  }
}

// ------------------------------------------------------------------ attention
// Q,K [B,H,S,64] (Q pre-scaled by 0.125*log2e); Vt [B,H,64,S]; mask [B,S];
// ctx [B,S,D] bf16.  256 q/block as 8 waves x 32 q-rows (512 threads), KV tile
// 64, double-buffered.  Grid 512 blocks, XCD-swizzled (8 heads/XCD = 4MB KV,
// L2-resident).  S^T = mfma(kf, qf); mask bias is the MFMA C-init.  P -> PV
// A-frag in registers via pack_bf16 + permlane{32,16}_swap (distinct operands).
// osum via onef-MFMA (matrix pipe has slack; VALU is the bottleneck — R13 A/B).
// Softmax: p = exp2(s + mask*log2e - 16); out = (P V)/(P 1) — shift cancels.
__global__ __launch_bounds__(512, 4) void attn_kernel(const bf16* __restrict__ Q,
                                                      const bf16* __restrict__ K,
                                                      const bf16* __restrict__ Vt,
                                                      const float* __restrict__ mask,
                                                      bf16* __restrict__ ctx) {
  __shared__ __attribute__((aligned(16))) bf16 Ks[2][64 * 64];
  __shared__ __attribute__((aligned(16))) bf16 Vs[2][64 * 64];
  __shared__ __attribute__((aligned(16))) float cms[S_DIM];

  const int tid = threadIdx.x;
  const int wave = tid >> 6, lane = tid & 63;
  const int quad = lane >> 4, l16 = lane & 15;
  const int swz = xcd_swz<512>(blockIdx.y * 8 + blockIdx.x);
  const int bh = swz >> 3, b = bh >> 4, h = bh & 15;
  const int qt = swz & 7;  // 256 q-rows per block; 32 per wave

  // Q fragments in registers: 32 rows per wave
  const bf16* Qg = Q + ((size_t)bh * S_DIM + qt * 256 + wave * 32) * HD_DIM;
  bf16x8 qf[2][2];
#pragma unroll
  for (int nq = 0; nq < 2; ++nq)
#pragma unroll
    for (int ks = 0; ks < 2; ++ks)
      qf[nq][ks] = *(const bf16x8*)(Qg + (nq * 16 + l16) * HD_DIM + ks * 32 + quad * 8);

  // stage mask -> cms = mask*log2e - 16  (once; 512 threads x 4 floats)
  {
    const float* mp = mask + b * S_DIM + tid * 4;
    const float4 a = *(const float4*)(mp);
    f32x4 r0 = {fmaf(a.x, LOG2E, -16.f), fmaf(a.y, LOG2E, -16.f),
                fmaf(a.z, LOG2E, -16.f), fmaf(a.w, LOG2E, -16.f)};
    *(f32x4*)(cms + tid * 4) = r0;
  }

  bf16x8 onef;
#pragma unroll
  for (int j = 0; j < 8; ++j) onef[j] = (bf16)1.0f;

  const f32x4 zero = {0.f, 0.f, 0.f, 0.f};
  f32x4 o[2][4], osum[2];
#pragma unroll
  for (int nq = 0; nq < 2; ++nq) {
    osum[nq] = zero;
#pragma unroll
    for (int nh = 0; nh < 4; ++nh) o[nq][nh] = zero;
  }

  const bf16* Kg0 = K + (size_t)bh * S_DIM * HD_DIM;
  const bf16* Vg0 = Vt + (size_t)bh * HD_DIM * S_DIM;

  auto stage = [&](int t) {
    const int buf = t & 1;
    const bf16* Kg = Kg0 + (size_t)t * 64 * HD_DIM;
    const bf16* Vg = Vg0 + t * 64;
    const int c = wave;  // 8 chunks of 1024B, one per wave
    const int row = c * 8 + (lane >> 3);
    const int blk = (lane & 7) ^ (row & 7);
    gll16(Kg + (size_t)row * HD_DIM + blk * 8, &Ks[buf][c * 512 + lane * 8]);
    gll16(Vg + (size_t)row * S_DIM + blk * 8, &Vs[buf][c * 512 + lane * 8]);
  };
  stage(0);

  for (int t = 0; t < S_DIM / 64; ++t) {
    __syncthreads();  // per-wave vmcnt drain at barrier: tile t + cms ready
    if (t + 1 < S_DIM / 64) stage(t + 1);
    const bf16* ks_ = &Ks[t & 1][0];
    const bf16* vs_ = &Vs[t & 1][0];

#pragma unroll
    for (int half = 0; half < 2; ++half) {  // half == ks of PV; mt in {2h,2h+1}
      u32 pk[2][2][2];  // [nq][mtl][i]: packed bf16 pair, word = kv32/2
#pragma unroll
      for (int mtl = 0; mtl < 2; ++mtl) {
        const int mt = half * 2 + mtl;
        // mask bias as MFMA C-init: sc = cm (broadcast over l16)
        const f32x4 cm = *(const f32x4*)(cms + t * 64 + mt * 16 + quad * 4);
        f32x4 sc[2];
        sc[0] = cm;
        sc[1] = cm;
#pragma unroll
        for (int ks = 0; ks < 2; ++ks) {
          const int row = mt * 16 + l16;  // kv
          const bf16x8 kf =
              *(const bf16x8*)(ks_ + row * 64 + (((ks * 4 + quad) ^ (row & 7)) * 8));
#pragma unroll
          for (int nq = 0; nq < 2; ++nq)
            sc[nq] = __builtin_amdgcn_mfma_f32_16x16x32_bf16(kf, qf[nq][ks], sc[nq], 0, 0, 0);
        }
#pragma unroll
        for (int nq = 0; nq < 2; ++nq) {
          const float e0 = __builtin_amdgcn_exp2f(sc[nq][0]);
          const float e1 = __builtin_amdgcn_exp2f(sc[nq][1]);
          const float e2 = __builtin_amdgcn_exp2f(sc[nq][2]);
          const float e3 = __builtin_amdgcn_exp2f(sc[nq][3]);
          pk[nq][mtl][0] = pack_bf16(e0, e1);
          pk[nq][mtl][1] = pack_bf16(e2, e3);
        }
      }

      // V fragments for this ks-half
      bf16x8 vf[4];
#pragma unroll
      for (int nh = 0; nh < 4; ++nh) {
        const int vrow = nh * 16 + l16;
        vf[nh] = *(const bf16x8*)(vs_ + vrow * 64 + (((half * 4 + quad) ^ (vrow & 7)) * 8));
      }

      // redistribute P to A-frag layout + PV (compiler-visible builtins)
#pragma unroll
      for (int nq = 0; nq < 2; ++nq) {
        auto a0 = __builtin_amdgcn_permlane32_swap(pk[nq][0][0], pk[nq][1][0], false, false);
        auto a1 = __builtin_amdgcn_permlane32_swap(pk[nq][0][1], pk[nq][1][1], false, false);
        auto b0 = __builtin_amdgcn_permlane16_swap(a0[0], a0[1], false, false);
        auto b1 = __builtin_amdgcn_permlane16_swap(a1[0], a1[1], false, false);
        union {
          u32 w[4];
          bf16x8 v;
        } pu;
        pu.w[0] = b0[0];  // jw=0: kv quad*8 + {0,1}
        pu.w[1] = b1[0];  // jw=1: kv quad*8 + {2,3}
        pu.w[2] = b0[1];  // jw=2: kv quad*8 + {4,5}
        pu.w[3] = b1[1];  // jw=3: kv quad*8 + {6,7}
        const bf16x8 pf = pu.v;
#pragma unroll
        for (int nh = 0; nh < 4; ++nh)
          o[nq][nh] = __builtin_amdgcn_mfma_f32_16x16x32_bf16(pf, vf[nh], o[nq][nh], 0, 0, 0);
        osum[nq] = __builtin_amdgcn_mfma_f32_16x16x32_bf16(pf, onef, osum[nq], 0, 0, 0);
      }
    }
  }

  // epilogue: out = o / osum (lane-local)
#pragma unroll
  for (int nq = 0; nq < 2; ++nq)
#pragma unroll
    for (int r = 0; r < 4; ++r) {
      const float inv = 1.0f / osum[nq][r];
      const int s = qt * 256 + wave * 32 + nq * 16 + quad * 4 + r;
#pragma unroll
      for (int nh = 0; nh < 4; ++nh)
        ctx[((size_t)b * S_DIM + s) * D_DIM + h * 64 + nh * 16 + l16] =
            (bf16)(o[nq][nh][r] * inv);
    }
}

// ------------------------------------------------------------------ launch
extern "C" void kernel_launch(void* const* d_in, const int* in_sizes, int n_in,
                              void* d_out, int out_size, void* d_ws, size_t ws_size,
                              hipStream_t stream) {
  const float* x    = (const float*)d_in[0];
  const float* mask = (const float*)d_in[1];
  const float* Wq   = (const float*)d_in[2];
  const float* bq   = (const float*)d_in[3];
  const float* Aq   = (const float*)d_in[4];
  const float* Bq   = (const float*)d_in[5];
  const float* Wk   = (const float*)d_in[6];
  const float* bk   = (const float*)d_in[7];
  const float* Wv   = (const float*)d_in[8];
  const float* bv   = (const float*)d_in[9];
  const float* Av   = (const float*)d_in[10];
  const float* Bv   = (const float*)d_in[11];
  const float* Wo   = (const float*)d_in[12];
  const float* bo   = (const float*)d_in[13];
  float* out = (float*)d_out;

  // workspace (xb aliased by Cw after QKV GEMM): ~75.5 MB total
  bf16* xb   = (bf16*)d_ws;                        // 16.8 MB (dead after QKV GEMM)
  bf16* wqkv = xb + (size_t)M_DIM * D_DIM;         // 6.3 MB  [wq;wk;wv]
  bf16* wo   = wqkv + (size_t)3 * D_DIM * D_DIM;   // 2.1 MB
  bf16* Qw   = wo + (size_t)D_DIM * D_DIM;         // 16.8 MB each
  bf16* Kw   = Qw + (size_t)M_DIM * D_DIM;
  bf16* Vw   = Kw + (size_t)M_DIM * D_DIM;
  bf16* Cw   = xb;                                 // alias: ctx reuses xb

  prepare_kernel<<<4096 + 4 * D_DIM * D_DIM / 256, 256, 0, stream>>>(
      x, xb, Wq, Aq, Bq, Wk, Wv, Av, Bv, Wo, wqkv, wo);

  gemm_qkv_kernel<<<dim3(M_DIM / 128, 3 * D_DIM / 128), 512, 0, stream>>>(
      xb, wqkv, bq, bk, bv, Qw, Kw, Vw);

  attn_kernel<<<dim3(S_DIM / 256, B_DIM * H_DIM), 512, 0, stream>>>(Qw, Kw, Vw, mask, Cw);

  gemm_o_kernel<<<dim3(M_DIM / 128, D_DIM / 128), 512, 0, stream>>>(Cw, wo, bo, out);
}